// Round 2
// baseline (618.436 us; speedup 1.0000x reference)
//
#include <hip/hip_runtime.h>
#include <stdint.h>

#define D_MODEL 2048
#define L_SEQ   2048
#define BATCH   2
#define NH      16
#define NKV     4
#define HD      128
#define ROT     64
#define M_ROWS  (BATCH * L_SEQ)            // 4096
#define N_QKV   (D_MODEL + 2 * NKV * HD)   // 3072

typedef short bf16x8 __attribute__((ext_vector_type(8)));
typedef float f32x4  __attribute__((ext_vector_type(4)));

__device__ __forceinline__ unsigned short f2b(float f) {
  union { float f; unsigned u; } v; v.f = f;
  unsigned r = v.u + 0x7FFFu + ((v.u >> 16) & 1u);
  return (unsigned short)(r >> 16);
}

// ---------------- elementwise fp32 -> bf16 ----------------
__global__ void cvt_bf16_kernel(const float* __restrict__ in,
                                unsigned short* __restrict__ out, int n4) {
  int i = blockIdx.x * blockDim.x + threadIdx.x;
  if (i < n4) {
    float4 v = ((const float4*)in)[i];
    ushort4 o;
    o.x = f2b(v.x); o.y = f2b(v.y); o.z = f2b(v.z); o.w = f2b(v.w);
    ((ushort4*)out)[i] = o;
  }
}

// ---------------- build Wqkv^T (3072 x 2048) bf16 ----------------
__global__ void build_wqkv_t(const float* __restrict__ Wq, const float* __restrict__ Wk,
                             const float* __restrict__ Wv, unsigned short* __restrict__ Wt) {
  __shared__ float tile[32][33];
  int k0 = blockIdx.x * 32;
  int n0 = blockIdx.y * 32;
  const float* W; int c0, ldw;
  if (n0 < D_MODEL)            { W = Wq; c0 = n0;                 ldw = D_MODEL; }
  else if (n0 < D_MODEL + 512) { W = Wk; c0 = n0 - D_MODEL;       ldw = 512; }
  else                         { W = Wv; c0 = n0 - D_MODEL - 512; ldw = 512; }
  int tx = threadIdx.x, ty = threadIdx.y;
#pragma unroll
  for (int i = 0; i < 32; i += 8)
    tile[ty + i][tx] = W[(size_t)(k0 + ty + i) * ldw + c0 + tx];
  __syncthreads();
#pragma unroll
  for (int i = 0; i < 32; i += 8)
    Wt[(size_t)(n0 + ty + i) * D_MODEL + k0 + tx] = f2b(tile[tx][ty + i]);
}

// ---------------- build Wo^T (2048 x 2048) bf16 ----------------
__global__ void build_wo_t(const float* __restrict__ Wo, unsigned short* __restrict__ Wt) {
  __shared__ float tile[32][33];
  int k0 = blockIdx.x * 32;
  int n0 = blockIdx.y * 32;
  int tx = threadIdx.x, ty = threadIdx.y;
#pragma unroll
  for (int i = 0; i < 32; i += 8)
    tile[ty + i][tx] = Wo[(size_t)(k0 + ty + i) * D_MODEL + n0 + tx];
  __syncthreads();
#pragma unroll
  for (int i = 0; i < 32; i += 8)
    Wt[(size_t)(n0 + ty + i) * D_MODEL + k0 + tx] = f2b(tile[tx][ty + i]);
}

// ---------------- m97-style bf16 GEMM, B^T input, fp32 out ----------------
#define BM 128
#define BN 128
#define BKg 64

__device__ __forceinline__ void async16(void* lds, const void* g) {
  __builtin_amdgcn_global_load_lds((const __attribute__((address_space(1))) void*)g,
                                   (__attribute__((address_space(3))) void*)lds, 16, 0, 0);
}

__global__ __launch_bounds__(256, 2)
void gemm_bt(const unsigned short* __restrict__ A, const unsigned short* __restrict__ Bt,
             float* __restrict__ C, int M, int N, int K) {
  __shared__ unsigned short As[BM * BKg];
  __shared__ unsigned short Bs[BN * BKg];
  int m0 = blockIdx.y * BM;
  int n0 = blockIdx.x * BN;
  int tid = threadIdx.x;
  int lane = tid & 63;
  int wave = __builtin_amdgcn_readfirstlane(tid >> 6);
  int wr = wave >> 1, wc = wave & 1;
  int lgrp = lane >> 4, lidx = lane & 15;

  f32x4 acc[4][4];
#pragma unroll
  for (int i = 0; i < 4; i++)
#pragma unroll
    for (int j = 0; j < 4; j++) { acc[i][j][0]=0.f; acc[i][j][1]=0.f; acc[i][j][2]=0.f; acc[i][j][3]=0.f; }

  for (int k0 = 0; k0 < K; k0 += BKg) {
#pragma unroll
    for (int iss = 0; iss < 4; iss++) {
      int idx = iss * 256 + tid;
      int row = idx >> 3, cch = idx & 7;
      int lbase = (iss * 256 + wave * 64) * 8;   // elements
      async16((void*)(As + lbase), A  + (size_t)(m0 + row) * K + k0 + cch * 8);
      async16((void*)(Bs + lbase), Bt + (size_t)(n0 + row) * K + k0 + cch * 8);
    }
    __syncthreads();
#pragma unroll
    for (int kk = 0; kk < BKg; kk += 32) {
      bf16x8 af[4], bfr[4];
#pragma unroll
      for (int i = 0; i < 4; i++) {
        af[i]  = *(const bf16x8*)(As + (wr * 64 + i * 16 + lidx) * BKg + kk + lgrp * 8);
        bfr[i] = *(const bf16x8*)(Bs + (wc * 64 + i * 16 + lidx) * BKg + kk + lgrp * 8);
      }
#pragma unroll
      for (int i = 0; i < 4; i++)
#pragma unroll
        for (int j = 0; j < 4; j++)
          acc[i][j] = __builtin_amdgcn_mfma_f32_16x16x32_bf16(af[i], bfr[j], acc[i][j], 0, 0, 0);
    }
    __syncthreads();
  }
#pragma unroll
  for (int i = 0; i < 4; i++) {
    int rowb = m0 + wr * 64 + i * 16 + lgrp * 4;
#pragma unroll
    for (int j = 0; j < 4; j++) {
      int col = n0 + wc * 64 + j * 16 + lidx;
#pragma unroll
      for (int r = 0; r < 4; r++)
        C[(size_t)(rowb + r) * N + col] = acc[i][j][r];
    }
  }
}

// ---------------- rope + qk-rmsnorm, writes Q/K bf16 per-(b,h) L x 128 ----------------
__global__ __launch_bounds__(256)
void rope_rms_kernel(const float* __restrict__ QKV, const float* __restrict__ cosp,
                     const float* __restrict__ sinp, unsigned short* __restrict__ Qb,
                     unsigned short* __restrict__ Kb) {
  int row = blockIdx.x;                    // b*L + l
  int b = row >> 11, l = row & 2047;
  int lane = threadIdx.x & 63;
  int wave = threadIdx.x >> 6;
  const float* src = QKV + (size_t)row * N_QKV;
  float c = cosp[l * ROT + lane];
  float s = sinp[l * ROT + lane];
  for (int hh = wave; hh < NH + NKV; hh += 4) {
    bool isq = hh < NH;
    int col0 = isq ? hh * HD : D_MODEL + (hh - NH) * HD;
    float x1 = src[col0 + lane];
    float x2 = src[col0 + 64 + lane];
    float o1 = x1 * c - x2 * s;
    float o2 = x2 * c + x1 * s;
    float ss = o1 * o1 + o2 * o2;
#pragma unroll
    for (int mk = 1; mk < 64; mk <<= 1) ss += __shfl_xor(ss, mk, 64);
    float rn = rsqrtf(ss * (1.f / 128.f) + 1e-6f);
    if (isq) rn *= 0.08838834764831845f;   // fold 1/sqrt(HD) into Q
    o1 *= rn; o2 *= rn;
    unsigned short* dst = isq ? (Qb + ((size_t)(b * NH + hh) * L_SEQ + l) * HD)
                              : (Kb + ((size_t)(b * NKV + (hh - NH)) * L_SEQ + l) * HD);
    dst[lane]      = f2b(o1);
    dst[lane + 64] = f2b(o2);
  }
}

// ---------------- V^T build: (b,kvh) 128 x L bf16 ----------------
__global__ void vt_build(const float* __restrict__ QKV, unsigned short* __restrict__ Vt) {
  __shared__ float tile[32][33];
  int z = blockIdx.z;                      // b*NKV + kh
  int l0 = blockIdx.x * 32;
  int d0 = blockIdx.y * 32;
  int b = z >> 2, kh = z & 3;
  int tx = threadIdx.x, ty = threadIdx.y;
  int colbase = D_MODEL + NKV * HD + kh * HD + d0;
#pragma unroll
  for (int i = 0; i < 32; i += 8)
    tile[ty + i][tx] = QKV[(size_t)(b * L_SEQ + l0 + ty + i) * N_QKV + colbase + tx];
  __syncthreads();
#pragma unroll
  for (int i = 0; i < 32; i += 8)
    Vt[((size_t)z * HD + d0 + ty + i) * L_SEQ + l0 + tx] = f2b(tile[tx][ty + i]);
}

// ---------------- flash attention: 1 wave, QBLK=16, KVBLK=32, causal ----------------
__global__ __launch_bounds__(64)
void attn_kernel(const unsigned short* __restrict__ Qb, const unsigned short* __restrict__ Kb,
                 const unsigned short* __restrict__ Vt, unsigned short* __restrict__ AttO) {
  __shared__ unsigned short P[16 * 32];
  int qb = blockIdx.x;
  int bh = blockIdx.y;
  int b = bh >> 4, h = bh & 15, kh = h >> 2;
  int q0 = qb * 16;
  int lane = threadIdx.x;
  int lgrp = lane >> 4, lidx = lane & 15;

  const unsigned short* Q = Qb + ((size_t)(b * NH + h) * L_SEQ + q0) * HD;
  const unsigned short* K = Kb + (size_t)(b * NKV + kh) * L_SEQ * HD;
  const unsigned short* V = Vt + (size_t)(b * NKV + kh) * HD * L_SEQ;   // [128][L]

  bf16x8 aq[4];
#pragma unroll
  for (int c = 0; c < 4; c++)
    aq[c] = *(const bf16x8*)(Q + lidx * HD + c * 32 + lgrp * 8);

  float m_r[4], l_r[4];
  f32x4 o[8];
#pragma unroll
  for (int r = 0; r < 4; r++) { m_r[r] = -1e30f; l_r[r] = 0.f; }
#pragma unroll
  for (int ch = 0; ch < 8; ch++) { o[ch][0]=0.f; o[ch][1]=0.f; o[ch][2]=0.f; o[ch][3]=0.f; }

  for (int kv0 = 0; kv0 < q0 + 16; kv0 += 32) {
    f32x4 sa[2];
    sa[0][0]=0.f; sa[0][1]=0.f; sa[0][2]=0.f; sa[0][3]=0.f;
    sa[1][0]=0.f; sa[1][1]=0.f; sa[1][2]=0.f; sa[1][3]=0.f;
#pragma unroll
    for (int n = 0; n < 2; n++) {
      const unsigned short* Kr = K + (size_t)(kv0 + n * 16 + lidx) * HD + lgrp * 8;
#pragma unroll
      for (int c = 0; c < 4; c++) {
        bf16x8 bk = *(const bf16x8*)(Kr + c * 32);
        sa[n] = __builtin_amdgcn_mfma_f32_16x16x32_bf16(aq[c], bk, sa[n], 0, 0, 0);
      }
    }
#pragma unroll
    for (int r = 0; r < 4; r++) {
      int row = q0 + lgrp * 4 + r;
      float v0 = (kv0 + lidx      <= row) ? sa[0][r] : -1e30f;
      float v1 = (kv0 + 16 + lidx <= row) ? sa[1][r] : -1e30f;
      float mx = fmaxf(v0, v1);
#pragma unroll
      for (int mk = 1; mk < 16; mk <<= 1) mx = fmaxf(mx, __shfl_xor(mx, mk, 64));
      float mnew = fmaxf(m_r[r], mx);
      float sf = __expf(m_r[r] - mnew);
      float p0 = __expf(v0 - mnew);
      float p1 = __expf(v1 - mnew);
      float ps = p0 + p1;
#pragma unroll
      for (int mk = 1; mk < 16; mk <<= 1) ps += __shfl_xor(ps, mk, 64);
      l_r[r] = l_r[r] * sf + ps;
      m_r[r] = mnew;
#pragma unroll
      for (int ch = 0; ch < 8; ch++) o[ch][r] *= sf;
      P[(lgrp * 4 + r) * 32 + lidx]      = f2b(p0);
      P[(lgrp * 4 + r) * 32 + 16 + lidx] = f2b(p1);
    }
    __syncthreads();
    bf16x8 ap = *(const bf16x8*)(P + lidx * 32 + lgrp * 8);
#pragma unroll
    for (int ch = 0; ch < 8; ch++) {
      const unsigned short* Vr = V + (size_t)(ch * 16 + lidx) * L_SEQ + kv0 + lgrp * 8;
      bf16x8 bv = *(const bf16x8*)Vr;
      o[ch] = __builtin_amdgcn_mfma_f32_16x16x32_bf16(ap, bv, o[ch], 0, 0, 0);
    }
    __syncthreads();
  }
#pragma unroll
  for (int r = 0; r < 4; r++) {
    float inv = 1.f / l_r[r];
    int grow = b * L_SEQ + q0 + lgrp * 4 + r;
#pragma unroll
    for (int ch = 0; ch < 8; ch++)
      AttO[(size_t)grow * D_MODEL + h * HD + ch * 16 + lidx] = f2b(o[ch][r] * inv);
  }
}

extern "C" void kernel_launch(void* const* d_in, const int* in_sizes, int n_in,
                              void* d_out, int out_size, void* d_ws, size_t ws_size,
                              hipStream_t stream) {
  const float* x    = (const float*)d_in[0];
  const float* cosp = (const float*)d_in[1];
  const float* sinp = (const float*)d_in[2];
  const float* Wq   = (const float*)d_in[3];
  const float* Wk   = (const float*)d_in[4];
  const float* Wv   = (const float*)d_in[5];
  const float* Wo   = (const float*)d_in[6];
  float* out = (float*)d_out;

  char* ws = (char*)d_ws;
  unsigned short* Xb   = (unsigned short*)ws; ws += (size_t)M_ROWS * D_MODEL * 2;
  unsigned short* Wt   = (unsigned short*)ws; ws += (size_t)N_QKV * D_MODEL * 2;
  unsigned short* Wot  = (unsigned short*)ws; ws += (size_t)D_MODEL * D_MODEL * 2;
  float*          QKV  = (float*)ws;          ws += (size_t)M_ROWS * N_QKV * 4;
  unsigned short* Qb   = (unsigned short*)ws; ws += (size_t)BATCH * NH * L_SEQ * HD * 2;
  unsigned short* Kb   = (unsigned short*)ws; ws += (size_t)BATCH * NKV * L_SEQ * HD * 2;
  unsigned short* Vt   = (unsigned short*)ws; ws += (size_t)BATCH * NKV * HD * L_SEQ * 2;
  unsigned short* AttO = (unsigned short*)ws; ws += (size_t)M_ROWS * D_MODEL * 2;

  cvt_bf16_kernel<<<(M_ROWS * D_MODEL / 4 + 255) / 256, 256, 0, stream>>>(x, Xb, M_ROWS * D_MODEL / 4);
  build_wqkv_t<<<dim3(64, 96), dim3(32, 8), 0, stream>>>(Wq, Wk, Wv, Wt);
  build_wo_t<<<dim3(64, 64), dim3(32, 8), 0, stream>>>(Wo, Wot);
  gemm_bt<<<dim3(N_QKV / BN, M_ROWS / BM), 256, 0, stream>>>(Xb, Wt, QKV, M_ROWS, N_QKV, D_MODEL);
  rope_rms_kernel<<<M_ROWS, 256, 0, stream>>>(QKV, cosp, sinp, Qb, Kb);
  vt_build<<<dim3(64, 4, 8), dim3(32, 8), 0, stream>>>(QKV, Vt);
  attn_kernel<<<dim3(L_SEQ / 16, BATCH * NH), 64, 0, stream>>>(Qb, Kb, Vt, AttO);
  gemm_bt<<<dim3(D_MODEL / BN, M_ROWS / BM), 256, 0, stream>>>(AttO, Wot, out, M_ROWS, D_MODEL, D_MODEL);
}

// Round 3
// 395.519 us; speedup vs baseline: 1.5636x; 1.5636x over previous
//
#include <hip/hip_runtime.h>
#include <stdint.h>

#define D_MODEL 2048
#define L_SEQ   2048
#define BATCH   2
#define NH      16
#define NKV     4
#define HD      128
#define ROT     64
#define M_ROWS  (BATCH * L_SEQ)            // 4096
#define N_QKV   (D_MODEL + 2 * NKV * HD)   // 3072

typedef short bf16x8 __attribute__((ext_vector_type(8)));
typedef float f32x4  __attribute__((ext_vector_type(4)));
typedef float f32x16 __attribute__((ext_vector_type(16)));

__device__ __forceinline__ unsigned short f2b(float f) {
  union { float f; unsigned u; } v; v.f = f;
  unsigned r = v.u + 0x7FFFu + ((v.u >> 16) & 1u);
  return (unsigned short)(r >> 16);
}

__device__ __forceinline__ unsigned cvtpk_bf16(float a, float b) {
  unsigned r;
  asm("v_cvt_pk_bf16_f32 %0, %1, %2" : "=v"(r) : "v"(a), "v"(b));
  return r;
}

// ---------------- elementwise fp32 -> bf16 ----------------
__global__ void cvt_bf16_kernel(const float* __restrict__ in,
                                unsigned short* __restrict__ out, int n4) {
  int i = blockIdx.x * blockDim.x + threadIdx.x;
  if (i < n4) {
    float4 v = ((const float4*)in)[i];
    ushort4 o;
    o.x = f2b(v.x); o.y = f2b(v.y); o.z = f2b(v.z); o.w = f2b(v.w);
    ((ushort4*)out)[i] = o;
  }
}

// ---------------- build Wqkv^T (3072 x 2048) bf16 ----------------
__global__ void build_wqkv_t(const float* __restrict__ Wq, const float* __restrict__ Wk,
                             const float* __restrict__ Wv, unsigned short* __restrict__ Wt) {
  __shared__ float tile[32][33];
  int k0 = blockIdx.x * 32;
  int n0 = blockIdx.y * 32;
  const float* W; int c0, ldw;
  if (n0 < D_MODEL)            { W = Wq; c0 = n0;                 ldw = D_MODEL; }
  else if (n0 < D_MODEL + 512) { W = Wk; c0 = n0 - D_MODEL;       ldw = 512; }
  else                         { W = Wv; c0 = n0 - D_MODEL - 512; ldw = 512; }
  int tx = threadIdx.x, ty = threadIdx.y;
#pragma unroll
  for (int i = 0; i < 32; i += 8)
    tile[ty + i][tx] = W[(size_t)(k0 + ty + i) * ldw + c0 + tx];
  __syncthreads();
#pragma unroll
  for (int i = 0; i < 32; i += 8)
    Wt[(size_t)(n0 + ty + i) * D_MODEL + k0 + tx] = f2b(tile[tx][ty + i]);
}

// ---------------- build Wo^T (2048 x 2048) bf16 ----------------
__global__ void build_wo_t(const float* __restrict__ Wo, unsigned short* __restrict__ Wt) {
  __shared__ float tile[32][33];
  int k0 = blockIdx.x * 32;
  int n0 = blockIdx.y * 32;
  int tx = threadIdx.x, ty = threadIdx.y;
#pragma unroll
  for (int i = 0; i < 32; i += 8)
    tile[ty + i][tx] = Wo[(size_t)(k0 + ty + i) * D_MODEL + n0 + tx];
  __syncthreads();
#pragma unroll
  for (int i = 0; i < 32; i += 8)
    Wt[(size_t)(n0 + ty + i) * D_MODEL + k0 + tx] = f2b(tile[tx][ty + i]);
}

// ---------------- m97-style bf16 GEMM, B^T input, fp32 out ----------------
#define BM 128
#define BN 128
#define BKg 64

__device__ __forceinline__ void async16(void* lds, const void* g) {
  __builtin_amdgcn_global_load_lds((const __attribute__((address_space(1))) void*)g,
                                   (__attribute__((address_space(3))) void*)lds, 16, 0, 0);
}

__global__ __launch_bounds__(256, 2)
void gemm_bt(const unsigned short* __restrict__ A, const unsigned short* __restrict__ Bt,
             float* __restrict__ C, int M, int N, int K) {
  __shared__ unsigned short As[BM * BKg];
  __shared__ unsigned short Bs[BN * BKg];
  int m0 = blockIdx.y * BM;
  int n0 = blockIdx.x * BN;
  int tid = threadIdx.x;
  int lane = tid & 63;
  int wave = __builtin_amdgcn_readfirstlane(tid >> 6);
  int wr = wave >> 1, wc = wave & 1;
  int lgrp = lane >> 4, lidx = lane & 15;

  f32x4 acc[4][4];
#pragma unroll
  for (int i = 0; i < 4; i++)
#pragma unroll
    for (int j = 0; j < 4; j++) { acc[i][j][0]=0.f; acc[i][j][1]=0.f; acc[i][j][2]=0.f; acc[i][j][3]=0.f; }

  for (int k0 = 0; k0 < K; k0 += BKg) {
#pragma unroll
    for (int iss = 0; iss < 4; iss++) {
      int idx = iss * 256 + tid;
      int row = idx >> 3, cch = idx & 7;
      int lbase = (iss * 256 + wave * 64) * 8;   // elements
      async16((void*)(As + lbase), A  + (size_t)(m0 + row) * K + k0 + cch * 8);
      async16((void*)(Bs + lbase), Bt + (size_t)(n0 + row) * K + k0 + cch * 8);
    }
    __syncthreads();
#pragma unroll
    for (int kk = 0; kk < BKg; kk += 32) {
      bf16x8 af[4], bfr[4];
#pragma unroll
      for (int i = 0; i < 4; i++) {
        af[i]  = *(const bf16x8*)(As + (wr * 64 + i * 16 + lidx) * BKg + kk + lgrp * 8);
        bfr[i] = *(const bf16x8*)(Bs + (wc * 64 + i * 16 + lidx) * BKg + kk + lgrp * 8);
      }
#pragma unroll
      for (int i = 0; i < 4; i++)
#pragma unroll
        for (int j = 0; j < 4; j++)
          acc[i][j] = __builtin_amdgcn_mfma_f32_16x16x32_bf16(af[i], bfr[j], acc[i][j], 0, 0, 0);
    }
    __syncthreads();
  }
#pragma unroll
  for (int i = 0; i < 4; i++) {
    int rowb = m0 + wr * 64 + i * 16 + lgrp * 4;
#pragma unroll
    for (int j = 0; j < 4; j++) {
      int col = n0 + wc * 64 + j * 16 + lidx;
#pragma unroll
      for (int r = 0; r < 4; r++)
        C[(size_t)(rowb + r) * N + col] = acc[i][j][r];
    }
  }
}

// ---------------- rope + qk-rmsnorm, writes Q/K bf16 per-(b,h) L x 128 ----------------
__global__ __launch_bounds__(256)
void rope_rms_kernel(const float* __restrict__ QKV, const float* __restrict__ cosp,
                     const float* __restrict__ sinp, unsigned short* __restrict__ Qb,
                     unsigned short* __restrict__ Kb) {
  int row = blockIdx.x;                    // b*L + l
  int b = row >> 11, l = row & 2047;
  int lane = threadIdx.x & 63;
  int wave = threadIdx.x >> 6;
  const float* src = QKV + (size_t)row * N_QKV;
  float c = cosp[l * ROT + lane];
  float s = sinp[l * ROT + lane];
  for (int hh = wave; hh < NH + NKV; hh += 4) {
    bool isq = hh < NH;
    int col0 = isq ? hh * HD : D_MODEL + (hh - NH) * HD;
    float x1 = src[col0 + lane];
    float x2 = src[col0 + 64 + lane];
    float o1 = x1 * c - x2 * s;
    float o2 = x2 * c + x1 * s;
    float ss = o1 * o1 + o2 * o2;
#pragma unroll
    for (int mk = 1; mk < 64; mk <<= 1) ss += __shfl_xor(ss, mk, 64);
    float rn = rsqrtf(ss * (1.f / 128.f) + 1e-6f);
    if (isq) rn *= 0.08838834764831845f;   // fold 1/sqrt(HD) into Q
    o1 *= rn; o2 *= rn;
    unsigned short* dst = isq ? (Qb + ((size_t)(b * NH + hh) * L_SEQ + l) * HD)
                              : (Kb + ((size_t)(b * NKV + (hh - NH)) * L_SEQ + l) * HD);
    dst[lane]      = f2b(o1);
    dst[lane + 64] = f2b(o2);
  }
}

// ---------------- V^T build: (b,kvh) 128 x L bf16 ----------------
__global__ void vt_build(const float* __restrict__ QKV, unsigned short* __restrict__ Vt) {
  __shared__ float tile[32][33];
  int z = blockIdx.z;                      // b*NKV + kh
  int l0 = blockIdx.x * 32;
  int d0 = blockIdx.y * 32;
  int b = z >> 2, kh = z & 3;
  int tx = threadIdx.x, ty = threadIdx.y;
  int colbase = D_MODEL + NKV * HD + kh * HD + d0;
#pragma unroll
  for (int i = 0; i < 32; i += 8)
    tile[ty + i][tx] = QKV[(size_t)(b * L_SEQ + l0 + ty + i) * N_QKV + colbase + tx];
  __syncthreads();
#pragma unroll
  for (int i = 0; i < 32; i += 8)
    Vt[((size_t)z * HD + d0 + ty + i) * L_SEQ + l0 + tx] = f2b(tile[tx][ty + i]);
}

// ---------------- flash attention: swapped-QK^T, 1 wave = 32 q-rows, no main-loop LDS ----------------
// S^T = mfma_32x32x16(A=K, B=Q): lane holds col q = lane&31, 16 kv rows/reg.
// 32x32 C/D: row=(reg&3)+8*(reg>>2)+4*(lane>>5), col=lane&31  [m74/m101]
// A/B input: row|col = lane&31, k = (lane>>5)*8 + j
__global__ __launch_bounds__(64)
void attn32_kernel(const unsigned short* __restrict__ Qb, const unsigned short* __restrict__ Kb,
                   const unsigned short* __restrict__ Vt, unsigned short* __restrict__ AttO) {
  __shared__ float tr[32][33];
  int idx = blockIdx.x;
  int qb = 63 - (idx >> 5);                // descending work (LPT) over 64 q-tiles
  int bh = idx & 31;
  int b = bh >> 4, h = bh & 15, kh = h >> 2;
  int q0 = qb * 32;
  int lane = threadIdx.x;
  int col = lane & 31;                     // this lane's q-row within tile
  int hi  = lane >> 5;

  const unsigned short* Q = Qb + ((size_t)(b * NH + h) * L_SEQ + q0) * HD;
  const unsigned short* K = Kb + (size_t)(b * NKV + kh) * L_SEQ * HD;
  const unsigned short* V = Vt + (size_t)(b * NKV + kh) * HD * L_SEQ;   // [128][L]

  bf16x8 qf[8];
#pragma unroll
  for (int c = 0; c < 8; c++)
    qf[c] = *(const bf16x8*)(Q + (size_t)col * HD + c * 16 + hi * 8);

  f32x16 o[4];
#pragma unroll
  for (int d0 = 0; d0 < 4; d0++)
#pragma unroll
    for (int r = 0; r < 16; r++) o[d0][r] = 0.f;

  float m = -1e30f, lsum = 0.f;

  for (int kv0 = 0; kv0 <= q0; kv0 += 32) {
    // ---- S^T tile: 8 mfma over d=128 ----
    f32x16 s;
#pragma unroll
    for (int r = 0; r < 16; r++) s[r] = 0.f;
#pragma unroll
    for (int c = 0; c < 8; c++) {
      bf16x8 kf = *(const bf16x8*)(K + (size_t)(kv0 + col) * HD + c * 16 + hi * 8);
      s = __builtin_amdgcn_mfma_f32_32x32x16_bf16(kf, qf[c], s, 0, 0, 0);
    }
    // ---- causal mask (diagonal tile only) ----
    if (kv0 == q0) {
#pragma unroll
      for (int r = 0; r < 16; r++) {
        int kvl = (r & 3) + 8 * (r >> 2) + 4 * hi;
        if (kvl > col) s[r] = -1e30f;
      }
    }
    // ---- online softmax, fully in-register ----
    float mx = s[0];
#pragma unroll
    for (int r = 1; r < 16; r++) mx = fmaxf(mx, s[r]);
    mx = fmaxf(mx, __shfl_xor(mx, 32, 64));
    if (!__all(mx <= m + 8.f)) {           // defer-max (T13)
      float mnew = fmaxf(m, mx);
      float sf = __expf(m - mnew);
      lsum *= sf;
#pragma unroll
      for (int d0 = 0; d0 < 4; d0++)
#pragma unroll
        for (int r = 0; r < 16; r++) o[d0][r] *= sf;
      m = mnew;
    }
    float p[16];
    float ps = 0.f;
#pragma unroll
    for (int r = 0; r < 16; r++) { p[r] = __expf(s[r] - m); ps += p[r]; }
    lsum += ps + __shfl_xor(ps, 32, 64);
    // ---- P -> bf16 B-fragments (cvt_pk + half-exchange), PV ----
#pragma unroll
    for (int w = 0; w < 2; w++) {
      unsigned c01 = cvtpk_bf16(p[w*8+0], p[w*8+1]);
      unsigned c23 = cvtpk_bf16(p[w*8+2], p[w*8+3]);
      unsigned c45 = cvtpk_bf16(p[w*8+4], p[w*8+5]);
      unsigned c67 = cvtpk_bf16(p[w*8+6], p[w*8+7]);
      unsigned x01 = (unsigned)__shfl_xor((int)c01, 32, 64);
      unsigned x23 = (unsigned)__shfl_xor((int)c23, 32, 64);
      unsigned x45 = (unsigned)__shfl_xor((int)c45, 32, 64);
      unsigned x67 = (unsigned)__shfl_xor((int)c67, 32, 64);
      union { unsigned u[4]; bf16x8 v; } pb;
      pb.u[0] = hi ? x45 : c01;
      pb.u[1] = hi ? x67 : c23;
      pb.u[2] = hi ? c45 : x01;
      pb.u[3] = hi ? c67 : x23;
#pragma unroll
      for (int d0 = 0; d0 < 4; d0++) {
        bf16x8 vf = *(const bf16x8*)(V + (size_t)(d0 * 32 + col) * L_SEQ + kv0 + w * 16 + hi * 8);
        o[d0] = __builtin_amdgcn_mfma_f32_32x32x16_bf16(vf, pb.v, o[d0], 0, 0, 0);
      }
    }
  }

  // ---- epilogue: O^T -> O via LDS transpose, bf16 store ----
  float inv = 1.f / lsum;
  unsigned short* orow = AttO + (size_t)(b * L_SEQ + q0 + col) * D_MODEL + h * HD;
#pragma unroll
  for (int d0 = 0; d0 < 4; d0++) {
#pragma unroll
    for (int r = 0; r < 16; r++)
      tr[(r & 3) + 8 * (r >> 2) + 4 * hi][col] = o[d0][r] * inv;
    __syncthreads();
    union { unsigned u[8]; } pk;
#pragma unroll
    for (int t = 0; t < 8; t++) {
      float a  = tr[hi * 16 + 2 * t][col];
      float bb = tr[hi * 16 + 2 * t + 1][col];
      pk.u[t] = ((unsigned)f2b(a)) | (((unsigned)f2b(bb)) << 16);
    }
    *(uint4*)(orow + d0 * 32 + hi * 16)     = *(uint4*)&pk.u[0];
    *(uint4*)(orow + d0 * 32 + hi * 16 + 8) = *(uint4*)&pk.u[4];
    __syncthreads();
  }
}

extern "C" void kernel_launch(void* const* d_in, const int* in_sizes, int n_in,
                              void* d_out, int out_size, void* d_ws, size_t ws_size,
                              hipStream_t stream) {
  const float* x    = (const float*)d_in[0];
  const float* cosp = (const float*)d_in[1];
  const float* sinp = (const float*)d_in[2];
  const float* Wq   = (const float*)d_in[3];
  const float* Wk   = (const float*)d_in[4];
  const float* Wv   = (const float*)d_in[5];
  const float* Wo   = (const float*)d_in[6];
  float* out = (float*)d_out;

  char* ws = (char*)d_ws;
  unsigned short* Xb   = (unsigned short*)ws; ws += (size_t)M_ROWS * D_MODEL * 2;
  unsigned short* Wt   = (unsigned short*)ws; ws += (size_t)N_QKV * D_MODEL * 2;
  unsigned short* Wot  = (unsigned short*)ws; ws += (size_t)D_MODEL * D_MODEL * 2;
  float*          QKV  = (float*)ws;          ws += (size_t)M_ROWS * N_QKV * 4;
  unsigned short* Qb   = (unsigned short*)ws; ws += (size_t)BATCH * NH * L_SEQ * HD * 2;
  unsigned short* Kb   = (unsigned short*)ws; ws += (size_t)BATCH * NKV * L_SEQ * HD * 2;
  unsigned short* Vt   = (unsigned short*)ws; ws += (size_t)BATCH * NKV * HD * L_SEQ * 2;
  unsigned short* AttO = (unsigned short*)ws; ws += (size_t)M_ROWS * D_MODEL * 2;

  cvt_bf16_kernel<<<(M_ROWS * D_MODEL / 4 + 255) / 256, 256, 0, stream>>>(x, Xb, M_ROWS * D_MODEL / 4);
  build_wqkv_t<<<dim3(64, 96), dim3(32, 8), 0, stream>>>(Wq, Wk, Wv, Wt);
  build_wo_t<<<dim3(64, 64), dim3(32, 8), 0, stream>>>(Wo, Wot);
  gemm_bt<<<dim3(N_QKV / BN, M_ROWS / BM), 256, 0, stream>>>(Xb, Wt, QKV, M_ROWS, N_QKV, D_MODEL);
  rope_rms_kernel<<<M_ROWS, 256, 0, stream>>>(QKV, cosp, sinp, Qb, Kb);
  vt_build<<<dim3(64, 4, 8), dim3(32, 8), 0, stream>>>(QKV, Vt);
  attn32_kernel<<<dim3(64 * 32), 64, 0, stream>>>(Qb, Kb, Vt, AttO);
  gemm_bt<<<dim3(D_MODEL / BN, M_ROWS / BM), 256, 0, stream>>>(AttO, Wot, out, M_ROWS, D_MODEL, D_MODEL);
}

// Round 4
// 390.470 us; speedup vs baseline: 1.5838x; 1.0129x over previous
//
#include <hip/hip_runtime.h>
#include <stdint.h>

#define D_MODEL 2048
#define L_SEQ   2048
#define BATCH   2
#define NH      16
#define NKV     4
#define HD      128
#define ROT     64
#define M_ROWS  (BATCH * L_SEQ)            // 4096
#define N_QKV   (D_MODEL + 2 * NKV * HD)   // 3072

typedef short bf16x8 __attribute__((ext_vector_type(8)));
typedef float f32x4  __attribute__((ext_vector_type(4)));
typedef float f32x16 __attribute__((ext_vector_type(16)));

__device__ __forceinline__ unsigned short f2b(float f) {
  union { float f; unsigned u; } v; v.f = f;
  unsigned r = v.u + 0x7FFFu + ((v.u >> 16) & 1u);
  return (unsigned short)(r >> 16);
}

__device__ __forceinline__ unsigned cvtpk_bf16(float a, float b) {
  unsigned r;
  asm("v_cvt_pk_bf16_f32 %0, %1, %2" : "=v"(r) : "v"(a), "v"(b));
  return r;
}

// ---------------- elementwise fp32 -> bf16 ----------------
__global__ void cvt_bf16_kernel(const float* __restrict__ in,
                                unsigned short* __restrict__ out, int n4) {
  int i = blockIdx.x * blockDim.x + threadIdx.x;
  if (i < n4) {
    float4 v = ((const float4*)in)[i];
    ushort4 o;
    o.x = f2b(v.x); o.y = f2b(v.y); o.z = f2b(v.z); o.w = f2b(v.w);
    ((ushort4*)out)[i] = o;
  }
}

// ---------------- build Wqkv^T (3072 x 2048) bf16 ----------------
__global__ void build_wqkv_t(const float* __restrict__ Wq, const float* __restrict__ Wk,
                             const float* __restrict__ Wv, unsigned short* __restrict__ Wt) {
  __shared__ float tile[32][33];
  int k0 = blockIdx.x * 32;
  int n0 = blockIdx.y * 32;
  const float* W; int c0, ldw;
  if (n0 < D_MODEL)            { W = Wq; c0 = n0;                 ldw = D_MODEL; }
  else if (n0 < D_MODEL + 512) { W = Wk; c0 = n0 - D_MODEL;       ldw = 512; }
  else                         { W = Wv; c0 = n0 - D_MODEL - 512; ldw = 512; }
  int tx = threadIdx.x, ty = threadIdx.y;
#pragma unroll
  for (int i = 0; i < 32; i += 8)
    tile[ty + i][tx] = W[(size_t)(k0 + ty + i) * ldw + c0 + tx];
  __syncthreads();
#pragma unroll
  for (int i = 0; i < 32; i += 8)
    Wt[(size_t)(n0 + ty + i) * D_MODEL + k0 + tx] = f2b(tile[tx][ty + i]);
}

// ---------------- build Wo^T (2048 x 2048) bf16 ----------------
__global__ void build_wo_t(const float* __restrict__ Wo, unsigned short* __restrict__ Wt) {
  __shared__ float tile[32][33];
  int k0 = blockIdx.x * 32;
  int n0 = blockIdx.y * 32;
  int tx = threadIdx.x, ty = threadIdx.y;
#pragma unroll
  for (int i = 0; i < 32; i += 8)
    tile[ty + i][tx] = Wo[(size_t)(k0 + ty + i) * D_MODEL + n0 + tx];
  __syncthreads();
#pragma unroll
  for (int i = 0; i < 32; i += 8)
    Wt[(size_t)(n0 + ty + i) * D_MODEL + k0 + tx] = f2b(tile[tx][ty + i]);
}

// ---------------- m97-style bf16 GEMM, B^T input, fp32 out ----------------
#define BM 128
#define BN 128
#define BKg 64

__device__ __forceinline__ void async16(void* lds, const void* g) {
  __builtin_amdgcn_global_load_lds((const __attribute__((address_space(1))) void*)g,
                                   (__attribute__((address_space(3))) void*)lds, 16, 0, 0);
}

__global__ __launch_bounds__(256, 2)
void gemm_bt(const unsigned short* __restrict__ A, const unsigned short* __restrict__ Bt,
             float* __restrict__ C, int M, int N, int K) {
  __shared__ unsigned short As[BM * BKg];
  __shared__ unsigned short Bs[BN * BKg];
  int m0 = blockIdx.y * BM;
  int n0 = blockIdx.x * BN;
  int tid = threadIdx.x;
  int lane = tid & 63;
  int wave = __builtin_amdgcn_readfirstlane(tid >> 6);
  int wr = wave >> 1, wc = wave & 1;
  int lgrp = lane >> 4, lidx = lane & 15;

  f32x4 acc[4][4];
#pragma unroll
  for (int i = 0; i < 4; i++)
#pragma unroll
    for (int j = 0; j < 4; j++) { acc[i][j][0]=0.f; acc[i][j][1]=0.f; acc[i][j][2]=0.f; acc[i][j][3]=0.f; }

  for (int k0 = 0; k0 < K; k0 += BKg) {
#pragma unroll
    for (int iss = 0; iss < 4; iss++) {
      int idx = iss * 256 + tid;
      int row = idx >> 3, cch = idx & 7;
      int lbase = (iss * 256 + wave * 64) * 8;   // elements
      async16((void*)(As + lbase), A  + (size_t)(m0 + row) * K + k0 + cch * 8);
      async16((void*)(Bs + lbase), Bt + (size_t)(n0 + row) * K + k0 + cch * 8);
    }
    __syncthreads();
#pragma unroll
    for (int kk = 0; kk < BKg; kk += 32) {
      bf16x8 af[4], bfr[4];
#pragma unroll
      for (int i = 0; i < 4; i++) {
        af[i]  = *(const bf16x8*)(As + (wr * 64 + i * 16 + lidx) * BKg + kk + lgrp * 8);
        bfr[i] = *(const bf16x8*)(Bs + (wc * 64 + i * 16 + lidx) * BKg + kk + lgrp * 8);
      }
#pragma unroll
      for (int i = 0; i < 4; i++)
#pragma unroll
        for (int j = 0; j < 4; j++)
          acc[i][j] = __builtin_amdgcn_mfma_f32_16x16x32_bf16(af[i], bfr[j], acc[i][j], 0, 0, 0);
    }
    __syncthreads();
  }
#pragma unroll
  for (int i = 0; i < 4; i++) {
    int rowb = m0 + wr * 64 + i * 16 + lgrp * 4;
#pragma unroll
    for (int j = 0; j < 4; j++) {
      int col = n0 + wc * 64 + j * 16 + lidx;
#pragma unroll
      for (int r = 0; r < 4; r++)
        C[(size_t)(rowb + r) * N + col] = acc[i][j][r];
    }
  }
}

// ---------------- rope + qk-rmsnorm, writes Q/K bf16 per-(b,h) L x 128 ----------------
__global__ __launch_bounds__(256)
void rope_rms_kernel(const float* __restrict__ QKV, const float* __restrict__ cosp,
                     const float* __restrict__ sinp, unsigned short* __restrict__ Qb,
                     unsigned short* __restrict__ Kb) {
  int row = blockIdx.x;                    // b*L + l
  int b = row >> 11, l = row & 2047;
  int lane = threadIdx.x & 63;
  int wave = threadIdx.x >> 6;
  const float* src = QKV + (size_t)row * N_QKV;
  float c = cosp[l * ROT + lane];
  float s = sinp[l * ROT + lane];
  for (int hh = wave; hh < NH + NKV; hh += 4) {
    bool isq = hh < NH;
    int col0 = isq ? hh * HD : D_MODEL + (hh - NH) * HD;
    float x1 = src[col0 + lane];
    float x2 = src[col0 + 64 + lane];
    float o1 = x1 * c - x2 * s;
    float o2 = x2 * c + x1 * s;
    float ss = o1 * o1 + o2 * o2;
#pragma unroll
    for (int mk = 1; mk < 64; mk <<= 1) ss += __shfl_xor(ss, mk, 64);
    float rn = rsqrtf(ss * (1.f / 128.f) + 1e-6f);
    if (isq) rn *= 0.08838834764831845f;   // fold 1/sqrt(HD) into Q
    o1 *= rn; o2 *= rn;
    unsigned short* dst = isq ? (Qb + ((size_t)(b * NH + hh) * L_SEQ + l) * HD)
                              : (Kb + ((size_t)(b * NKV + (hh - NH)) * L_SEQ + l) * HD);
    dst[lane]      = f2b(o1);
    dst[lane + 64] = f2b(o2);
  }
}

// ---------------- V^T build: (b,kvh) 128 x L bf16 ----------------
__global__ void vt_build(const float* __restrict__ QKV, unsigned short* __restrict__ Vt) {
  __shared__ float tile[32][33];
  int z = blockIdx.z;                      // b*NKV + kh
  int l0 = blockIdx.x * 32;
  int d0 = blockIdx.y * 32;
  int b = z >> 2, kh = z & 3;
  int tx = threadIdx.x, ty = threadIdx.y;
  int colbase = D_MODEL + NKV * HD + kh * HD + d0;
#pragma unroll
  for (int i = 0; i < 32; i += 8)
    tile[ty + i][tx] = QKV[(size_t)(b * L_SEQ + l0 + ty + i) * N_QKV + colbase + tx];
  __syncthreads();
#pragma unroll
  for (int i = 0; i < 32; i += 8)
    Vt[((size_t)z * HD + d0 + ty + i) * L_SEQ + l0 + tx] = f2b(tile[tx][ty + i]);
}

// ---------------- flash attention: swapped-QK^T, 1 wave = 32 q-rows ----------------
// S^T = mfma_32x32x16(A=K, B=Q): lane holds col q = lane&31, 16 kv rows/reg.
// 32x32 C/D: row=(reg&3)+8*(reg>>2)+4*(lane>>5), col=lane&31  [m74/m101]
// Load schedule (T14): K[t+1] prefetched right after QK^T(t) issues; V[t]
// batch-issued before softmax so it lands under the softmax VALU region.
__global__ __launch_bounds__(64, 2)
void attn32_kernel(const unsigned short* __restrict__ Qb, const unsigned short* __restrict__ Kb,
                   const unsigned short* __restrict__ Vt, unsigned short* __restrict__ AttO) {
  __shared__ float tr[32][33];
  int idx = blockIdx.x;
  int qb = 63 - (idx >> 5);                // descending work (LPT) over 64 q-tiles
  int bh = idx & 31;
  int b = bh >> 4, h = bh & 15, kh = h >> 2;
  int q0 = qb * 32;
  int lane = threadIdx.x;
  int col = lane & 31;                     // this lane's q-row within tile
  int hi  = lane >> 5;

  const unsigned short* Q = Qb + ((size_t)(b * NH + h) * L_SEQ + q0) * HD;
  const unsigned short* K = Kb + (size_t)(b * NKV + kh) * L_SEQ * HD;
  const unsigned short* V = Vt + (size_t)(b * NKV + kh) * HD * L_SEQ;   // [128][L]

  bf16x8 qf[8];
#pragma unroll
  for (int c = 0; c < 8; c++)
    qf[c] = *(const bf16x8*)(Q + (size_t)col * HD + c * 16 + hi * 8);

  f32x16 o[4];
#pragma unroll
  for (int d0 = 0; d0 < 4; d0++)
#pragma unroll
    for (int r = 0; r < 16; r++) o[d0][r] = 0.f;

  float m = -1e30f, lsum = 0.f;

  // prologue: K fragments for tile 0
  bf16x8 kf[8];
#pragma unroll
  for (int c = 0; c < 8; c++)
    kf[c] = *(const bf16x8*)(K + (size_t)col * HD + c * 16 + hi * 8);

  for (int kv0 = 0; kv0 <= q0; kv0 += 32) {
    // ---- S^T tile: 8 mfma over d=128, two independent chains ----
    f32x16 sA, sB;
#pragma unroll
    for (int r = 0; r < 16; r++) { sA[r] = 0.f; sB[r] = 0.f; }
#pragma unroll
    for (int c = 0; c < 4; c++)
      sA = __builtin_amdgcn_mfma_f32_32x32x16_bf16(kf[c], qf[c], sA, 0, 0, 0);
#pragma unroll
    for (int c = 4; c < 8; c++)
      sB = __builtin_amdgcn_mfma_f32_32x32x16_bf16(kf[c], qf[c], sB, 0, 0, 0);

    // ---- prefetch next K tile (clamped address when last tile) ----
    int kvn = (kv0 + 32 <= q0) ? (kv0 + 32) : kv0;
    bf16x8 kn[8];
#pragma unroll
    for (int c = 0; c < 8; c++)
      kn[c] = *(const bf16x8*)(K + (size_t)(kvn + col) * HD + c * 16 + hi * 8);

    // ---- batch-issue V loads for this tile ----
    bf16x8 vf[8];
#pragma unroll
    for (int w = 0; w < 2; w++)
#pragma unroll
      for (int d0 = 0; d0 < 4; d0++)
        vf[w * 4 + d0] = *(const bf16x8*)(V + (size_t)(d0 * 32 + col) * L_SEQ + kv0 + w * 16 + hi * 8);

    f32x16 s = sA + sB;
    // ---- causal mask (diagonal tile only) ----
    if (kv0 == q0) {
#pragma unroll
      for (int r = 0; r < 16; r++) {
        int kvl = (r & 3) + 8 * (r >> 2) + 4 * hi;
        if (kvl > col) s[r] = -1e30f;
      }
    }
    // ---- online softmax, fully in-register ----
    float mx = s[0];
#pragma unroll
    for (int r = 1; r < 16; r++) mx = fmaxf(mx, s[r]);
    mx = fmaxf(mx, __shfl_xor(mx, 32, 64));
    if (!__all(mx <= m + 8.f)) {           // defer-max (T13)
      float mnew = fmaxf(m, mx);
      float sf = __expf(m - mnew);
      lsum *= sf;
#pragma unroll
      for (int d0 = 0; d0 < 4; d0++)
#pragma unroll
        for (int r = 0; r < 16; r++) o[d0][r] *= sf;
      m = mnew;
    }
    float ps = 0.f;
#pragma unroll
    for (int r = 0; r < 16; r++) { s[r] = __expf(s[r] - m); ps += s[r]; }
    lsum += ps + __shfl_xor(ps, 32, 64);
    // ---- P -> bf16 B-fragments (cvt_pk + half-exchange), PV ----
#pragma unroll
    for (int w = 0; w < 2; w++) {
      unsigned c01 = cvtpk_bf16(s[w*8+0], s[w*8+1]);
      unsigned c23 = cvtpk_bf16(s[w*8+2], s[w*8+3]);
      unsigned c45 = cvtpk_bf16(s[w*8+4], s[w*8+5]);
      unsigned c67 = cvtpk_bf16(s[w*8+6], s[w*8+7]);
      unsigned x01 = (unsigned)__shfl_xor((int)c01, 32, 64);
      unsigned x23 = (unsigned)__shfl_xor((int)c23, 32, 64);
      unsigned x45 = (unsigned)__shfl_xor((int)c45, 32, 64);
      unsigned x67 = (unsigned)__shfl_xor((int)c67, 32, 64);
      union { unsigned u[4]; bf16x8 v; } pb;
      pb.u[0] = hi ? x45 : c01;
      pb.u[1] = hi ? x67 : c23;
      pb.u[2] = hi ? c45 : x01;
      pb.u[3] = hi ? c67 : x23;
#pragma unroll
      for (int d0 = 0; d0 < 4; d0++)
        o[d0] = __builtin_amdgcn_mfma_f32_32x32x16_bf16(vf[w * 4 + d0], pb.v, o[d0], 0, 0, 0);
    }
    // ---- rotate prefetched K into place ----
#pragma unroll
    for (int c = 0; c < 8; c++) kf[c] = kn[c];
  }

  // ---- epilogue: O^T -> O via LDS transpose, bf16 store ----
  float inv = 1.f / lsum;
  unsigned short* orow = AttO + (size_t)(b * L_SEQ + q0 + col) * D_MODEL + h * HD;
#pragma unroll
  for (int d0 = 0; d0 < 4; d0++) {
#pragma unroll
    for (int r = 0; r < 16; r++)
      tr[(r & 3) + 8 * (r >> 2) + 4 * hi][col] = o[d0][r] * inv;
    __syncthreads();
    union { unsigned u[8]; } pk;
#pragma unroll
    for (int t = 0; t < 8; t++) {
      float a  = tr[hi * 16 + 2 * t][col];
      float bb = tr[hi * 16 + 2 * t + 1][col];
      pk.u[t] = ((unsigned)f2b(a)) | (((unsigned)f2b(bb)) << 16);
    }
    *(uint4*)(orow + d0 * 32 + hi * 16)     = *(uint4*)&pk.u[0];
    *(uint4*)(orow + d0 * 32 + hi * 16 + 8) = *(uint4*)&pk.u[4];
    __syncthreads();
  }
}

extern "C" void kernel_launch(void* const* d_in, const int* in_sizes, int n_in,
                              void* d_out, int out_size, void* d_ws, size_t ws_size,
                              hipStream_t stream) {
  const float* x    = (const float*)d_in[0];
  const float* cosp = (const float*)d_in[1];
  const float* sinp = (const float*)d_in[2];
  const float* Wq   = (const float*)d_in[3];
  const float* Wk   = (const float*)d_in[4];
  const float* Wv   = (const float*)d_in[5];
  const float* Wo   = (const float*)d_in[6];
  float* out = (float*)d_out;

  char* ws = (char*)d_ws;
  unsigned short* Xb   = (unsigned short*)ws; ws += (size_t)M_ROWS * D_MODEL * 2;
  unsigned short* Wt   = (unsigned short*)ws; ws += (size_t)N_QKV * D_MODEL * 2;
  unsigned short* Wot  = (unsigned short*)ws; ws += (size_t)D_MODEL * D_MODEL * 2;
  float*          QKV  = (float*)ws;          ws += (size_t)M_ROWS * N_QKV * 4;
  unsigned short* Qb   = (unsigned short*)ws; ws += (size_t)BATCH * NH * L_SEQ * HD * 2;
  unsigned short* Kb   = (unsigned short*)ws; ws += (size_t)BATCH * NKV * L_SEQ * HD * 2;
  unsigned short* Vt   = (unsigned short*)ws; ws += (size_t)BATCH * NKV * HD * L_SEQ * 2;
  unsigned short* AttO = (unsigned short*)ws; ws += (size_t)M_ROWS * D_MODEL * 2;

  cvt_bf16_kernel<<<(M_ROWS * D_MODEL / 4 + 255) / 256, 256, 0, stream>>>(x, Xb, M_ROWS * D_MODEL / 4);
  build_wqkv_t<<<dim3(64, 96), dim3(32, 8), 0, stream>>>(Wq, Wk, Wv, Wt);
  build_wo_t<<<dim3(64, 64), dim3(32, 8), 0, stream>>>(Wo, Wot);
  gemm_bt<<<dim3(N_QKV / BN, M_ROWS / BM), 256, 0, stream>>>(Xb, Wt, QKV, M_ROWS, N_QKV, D_MODEL);
  rope_rms_kernel<<<M_ROWS, 256, 0, stream>>>(QKV, cosp, sinp, Qb, Kb);
  vt_build<<<dim3(64, 4, 8), dim3(32, 8), 0, stream>>>(QKV, Vt);
  attn32_kernel<<<dim3(64 * 32), 64, 0, stream>>>(Qb, Kb, Vt, AttO);
  gemm_bt<<<dim3(D_MODEL / BN, M_ROWS / BM), 256, 0, stream>>>(AttO, Wot, out, M_ROWS, D_MODEL, D_MODEL);
}

// Round 6
// 338.483 us; speedup vs baseline: 1.8271x; 1.1536x over previous
//
#include <hip/hip_runtime.h>
#include <stdint.h>

#define D_MODEL 2048
#define L_SEQ   2048
#define BATCH   2
#define NH      16
#define NKV     4
#define HD      128
#define ROT     64
#define M_ROWS  (BATCH * L_SEQ)            // 4096
#define N_QKV   (D_MODEL + 2 * NKV * HD)   // 3072

typedef short bf16x8 __attribute__((ext_vector_type(8)));
typedef float f32x4  __attribute__((ext_vector_type(4)));
typedef float f32x16 __attribute__((ext_vector_type(16)));

__device__ __forceinline__ unsigned short f2b(float f) {
  union { float f; unsigned u; } v; v.f = f;
  unsigned r = v.u + 0x7FFFu + ((v.u >> 16) & 1u);
  return (unsigned short)(r >> 16);
}

__device__ __forceinline__ unsigned cvtpk_bf16(float a, float b) {
  unsigned r;
  asm("v_cvt_pk_bf16_f32 %0, %1, %2" : "=v"(r) : "v"(a), "v"(b));
  return r;
}

// ---------------- elementwise fp32 -> bf16 ----------------
__global__ void cvt_bf16_kernel(const float* __restrict__ in,
                                unsigned short* __restrict__ out, int n4) {
  int i = blockIdx.x * blockDim.x + threadIdx.x;
  if (i < n4) {
    float4 v = ((const float4*)in)[i];
    ushort4 o;
    o.x = f2b(v.x); o.y = f2b(v.y); o.z = f2b(v.z); o.w = f2b(v.w);
    ((ushort4*)out)[i] = o;
  }
}

// ---------------- build Wqkv^T (3072 x 2048) bf16 ----------------
__global__ void build_wqkv_t(const float* __restrict__ Wq, const float* __restrict__ Wk,
                             const float* __restrict__ Wv, unsigned short* __restrict__ Wt) {
  __shared__ float tile[32][33];
  int k0 = blockIdx.x * 32;
  int n0 = blockIdx.y * 32;
  const float* W; int c0, ldw;
  if (n0 < D_MODEL)            { W = Wq; c0 = n0;                 ldw = D_MODEL; }
  else if (n0 < D_MODEL + 512) { W = Wk; c0 = n0 - D_MODEL;       ldw = 512; }
  else                         { W = Wv; c0 = n0 - D_MODEL - 512; ldw = 512; }
  int tx = threadIdx.x, ty = threadIdx.y;
#pragma unroll
  for (int i = 0; i < 32; i += 8)
    tile[ty + i][tx] = W[(size_t)(k0 + ty + i) * ldw + c0 + tx];
  __syncthreads();
#pragma unroll
  for (int i = 0; i < 32; i += 8)
    Wt[(size_t)(n0 + ty + i) * D_MODEL + k0 + tx] = f2b(tile[tx][ty + i]);
}

// ---------------- build Wo^T (2048 x 2048) bf16 ----------------
__global__ void build_wo_t(const float* __restrict__ Wo, unsigned short* __restrict__ Wt) {
  __shared__ float tile[32][33];
  int k0 = blockIdx.x * 32;
  int n0 = blockIdx.y * 32;
  int tx = threadIdx.x, ty = threadIdx.y;
#pragma unroll
  for (int i = 0; i < 32; i += 8)
    tile[ty + i][tx] = Wo[(size_t)(k0 + ty + i) * D_MODEL + n0 + tx];
  __syncthreads();
#pragma unroll
  for (int i = 0; i < 32; i += 8)
    Wt[(size_t)(n0 + ty + i) * D_MODEL + k0 + tx] = f2b(tile[tx][ty + i]);
}

// ---------------- m97-style bf16 GEMM, B^T input, fp32 out ----------------
#define BM 128
#define BN 128
#define BKg 64

__device__ __forceinline__ void async16(void* lds, const void* g) {
  __builtin_amdgcn_global_load_lds((const __attribute__((address_space(1))) void*)g,
                                   (__attribute__((address_space(3))) void*)lds, 16, 0, 0);
}

__global__ __launch_bounds__(256, 2)
void gemm_bt(const unsigned short* __restrict__ A, const unsigned short* __restrict__ Bt,
             float* __restrict__ C, int M, int N, int K) {
  __shared__ unsigned short As[BM * BKg];
  __shared__ unsigned short Bs[BN * BKg];
  int m0 = blockIdx.y * BM;
  int n0 = blockIdx.x * BN;
  int tid = threadIdx.x;
  int lane = tid & 63;
  int wave = __builtin_amdgcn_readfirstlane(tid >> 6);
  int wr = wave >> 1, wc = wave & 1;
  int lgrp = lane >> 4, lidx = lane & 15;

  f32x4 acc[4][4];
#pragma unroll
  for (int i = 0; i < 4; i++)
#pragma unroll
    for (int j = 0; j < 4; j++) { acc[i][j][0]=0.f; acc[i][j][1]=0.f; acc[i][j][2]=0.f; acc[i][j][3]=0.f; }

  for (int k0 = 0; k0 < K; k0 += BKg) {
#pragma unroll
    for (int iss = 0; iss < 4; iss++) {
      int idx = iss * 256 + tid;
      int row = idx >> 3, cch = idx & 7;
      int lbase = (iss * 256 + wave * 64) * 8;   // elements
      async16((void*)(As + lbase), A  + (size_t)(m0 + row) * K + k0 + cch * 8);
      async16((void*)(Bs + lbase), Bt + (size_t)(n0 + row) * K + k0 + cch * 8);
    }
    __syncthreads();
#pragma unroll
    for (int kk = 0; kk < BKg; kk += 32) {
      bf16x8 af[4], bfr[4];
#pragma unroll
      for (int i = 0; i < 4; i++) {
        af[i]  = *(const bf16x8*)(As + (wr * 64 + i * 16 + lidx) * BKg + kk + lgrp * 8);
        bfr[i] = *(const bf16x8*)(Bs + (wc * 64 + i * 16 + lidx) * BKg + kk + lgrp * 8);
      }
#pragma unroll
      for (int i = 0; i < 4; i++)
#pragma unroll
        for (int j = 0; j < 4; j++)
          acc[i][j] = __builtin_amdgcn_mfma_f32_16x16x32_bf16(af[i], bfr[j], acc[i][j], 0, 0, 0);
    }
    __syncthreads();
  }
#pragma unroll
  for (int i = 0; i < 4; i++) {
    int rowb = m0 + wr * 64 + i * 16 + lgrp * 4;
#pragma unroll
    for (int j = 0; j < 4; j++) {
      int col = n0 + wc * 64 + j * 16 + lidx;
#pragma unroll
      for (int r = 0; r < 4; r++)
        C[(size_t)(rowb + r) * N + col] = acc[i][j][r];
    }
  }
}

// ---------------- rope + qk-rmsnorm, writes Q/K bf16 per-(b,h) L x 128 ----------------
__global__ __launch_bounds__(256)
void rope_rms_kernel(const float* __restrict__ QKV, const float* __restrict__ cosp,
                     const float* __restrict__ sinp, unsigned short* __restrict__ Qb,
                     unsigned short* __restrict__ Kb) {
  int row = blockIdx.x;                    // b*L + l
  int b = row >> 11, l = row & 2047;
  int lane = threadIdx.x & 63;
  int wave = threadIdx.x >> 6;
  const float* src = QKV + (size_t)row * N_QKV;
  float c = cosp[l * ROT + lane];
  float s = sinp[l * ROT + lane];
  for (int hh = wave; hh < NH + NKV; hh += 4) {
    bool isq = hh < NH;
    int col0 = isq ? hh * HD : D_MODEL + (hh - NH) * HD;
    float x1 = src[col0 + lane];
    float x2 = src[col0 + 64 + lane];
    float o1 = x1 * c - x2 * s;
    float o2 = x2 * c + x1 * s;
    float ss = o1 * o1 + o2 * o2;
#pragma unroll
    for (int mk = 1; mk < 64; mk <<= 1) ss += __shfl_xor(ss, mk, 64);
    float rn = rsqrtf(ss * (1.f / 128.f) + 1e-6f);
    if (isq) rn *= 0.08838834764831845f;   // fold 1/sqrt(HD) into Q
    o1 *= rn; o2 *= rn;
    unsigned short* dst = isq ? (Qb + ((size_t)(b * NH + hh) * L_SEQ + l) * HD)
                              : (Kb + ((size_t)(b * NKV + (hh - NH)) * L_SEQ + l) * HD);
    dst[lane]      = f2b(o1);
    dst[lane + 64] = f2b(o2);
  }
}

// ---------------- V^T build: (b,kvh) 128 x L bf16 ----------------
__global__ void vt_build(const float* __restrict__ QKV, unsigned short* __restrict__ Vt) {
  __shared__ float tile[32][33];
  int z = blockIdx.z;                      // b*NKV + kh
  int l0 = blockIdx.x * 32;
  int d0 = blockIdx.y * 32;
  int b = z >> 2, kh = z & 3;
  int tx = threadIdx.x, ty = threadIdx.y;
  int colbase = D_MODEL + NKV * HD + kh * HD + d0;
#pragma unroll
  for (int i = 0; i < 32; i += 8)
    tile[ty + i][tx] = QKV[(size_t)(b * L_SEQ + l0 + ty + i) * N_QKV + colbase + tx];
  __syncthreads();
#pragma unroll
  for (int i = 0; i < 32; i += 8)
    Vt[((size_t)z * HD + d0 + ty + i) * L_SEQ + l0 + tx] = f2b(tile[tx][ty + i]);
}

// ---------------- flash attention: 4 waves/block share K,V via LDS ----------------
// Block = 128 q-rows of one (b,h); wave w owns rows [q0+32w, q0+32w+32).
// K tile [32][128] bf16 (8KB) + V^T tile [128][32] bf16 (8KB), double-buffered (32KB).
// T2 swizzle per rule #21: linear LDS dest (global_load_lds) + inverse-swizzled
// global SOURCE + swizzled ds_read. K: byte^=(row&7)<<4; V^T: byte^=(row&3)<<4.
// S^T = mfma_32x32x16(A=K, B=Q); 32x32 C/D: row=(reg&3)+8*(reg>>2)+4*hi, col=lane&31.
#define KSTRIDE 256   // bytes per K row (128 bf16)
#define VSTRIDE 64    // bytes per V^T row (32 bf16)
#define TILEB   16384 // K(8KB)+V(8KB) per buffer

__global__ __launch_bounds__(256, 2)
void attn128_kernel(const unsigned short* __restrict__ Qb, const unsigned short* __restrict__ Kb,
                    const unsigned short* __restrict__ Vt, unsigned short* __restrict__ AttO) {
  __shared__ char lds[2 * TILEB];
  int blk = blockIdx.x;
  int qt = 15 - (blk >> 5);                // LPT: long blocks first
  int bh = blk & 31;
  int b = bh >> 4, h = bh & 15, kh = h >> 2;
  int tid = threadIdx.x;
  int lane = tid & 63;
  int wave = __builtin_amdgcn_readfirstlane(tid >> 6);
  int col = lane & 31;
  int hi  = lane >> 5;
  int q0 = qt * 128 + wave * 32;

  const unsigned short* Q   = Qb + ((size_t)(b * NH + h) * L_SEQ + q0) * HD;
  const unsigned short* Kg  = Kb + (size_t)(b * NKV + kh) * L_SEQ * HD;
  const unsigned short* Vtg = Vt + (size_t)(b * NKV + kh) * HD * L_SEQ;  // [128][L]

  bf16x8 qf[8];
#pragma unroll
  for (int c = 0; c < 8; c++)
    qf[c] = *(const bf16x8*)(Q + (size_t)col * HD + c * 16 + hi * 8);

  f32x16 o[4];
#pragma unroll
  for (int d0 = 0; d0 < 4; d0++)
#pragma unroll
    for (int r = 0; r < 16; r++) o[d0][r] = 0.f;
  float m = -1e30f, lsum = 0.f;

  int NT = 4 * (qt + 1);                   // kv tiles this block walks
  int tmax = 4 * qt + wave;                // last tile this wave computes

  // ---- stage tile t into buffer base (global_load_lds, pre-swizzled source) ----
  auto STAGE = [&](char* base, int t) {
    int kv0 = t * 32;
    char* ldsK = base;
    char* ldsV = base + 8192;
    int wb = wave * 64;                    // wave-uniform slot base within round
#pragma unroll
    for (int r = 0; r < 2; r++) {
      int slot = r * 256 + tid;            // 0..511
      int row = slot >> 4, s16 = slot & 15;
      const char* src = (const char*)Kg + (size_t)(kv0 + row) * KSTRIDE + ((s16 ^ (row & 7)) << 4);
      async16(ldsK + (size_t)(r * 256 + wb) * 16, src);
    }
#pragma unroll
    for (int r = 0; r < 2; r++) {
      int slot = r * 256 + tid;
      int row = slot >> 2, s4 = slot & 3;
      const char* src = (const char*)Vtg + (size_t)row * (L_SEQ * 2) + (size_t)kv0 * 2 + ((s4 ^ (row & 3)) << 4);
      async16(ldsV + (size_t)(r * 256 + wb) * 16, src);
    }
  };

  STAGE(lds, 0);
  __syncthreads();                         // drains vmcnt -> tile 0 ready

  int cur = 0;
  for (int t = 0; t < NT; t++) {
    if (t + 1 < NT) STAGE(lds + (cur ^ 1) * TILEB, t + 1);

    if (t <= tmax) {
      const char* KB = lds + cur * TILEB;
      const char* VB = KB + 8192;
      int kv0 = t * 32;
      // ---- S^T: 8 mfma, two chains ----
      f32x16 sA, sB;
#pragma unroll
      for (int r = 0; r < 16; r++) { sA[r] = 0.f; sB[r] = 0.f; }
#pragma unroll
      for (int c = 0; c < 4; c++) {
        bf16x8 kf = *(const bf16x8*)(KB + col * KSTRIDE + ((32 * c + 16 * hi) ^ ((col & 7) << 4)));
        sA = __builtin_amdgcn_mfma_f32_32x32x16_bf16(kf, qf[c], sA, 0, 0, 0);
      }
#pragma unroll
      for (int c = 4; c < 8; c++) {
        bf16x8 kf = *(const bf16x8*)(KB + col * KSTRIDE + ((32 * c + 16 * hi) ^ ((col & 7) << 4)));
        sB = __builtin_amdgcn_mfma_f32_32x32x16_bf16(kf, qf[c], sB, 0, 0, 0);
      }
      f32x16 s = sA + sB;
      // ---- causal mask (diagonal tile only) ----
      if (t == tmax) {
#pragma unroll
        for (int r = 0; r < 16; r++) {
          int kvl = (r & 3) + 8 * (r >> 2) + 4 * hi;
          if (kvl > col) s[r] = -1e30f;
        }
      }
      // ---- online softmax, in-register ----
      float mx = s[0];
#pragma unroll
      for (int r = 1; r < 16; r++) mx = fmaxf(mx, s[r]);
      mx = fmaxf(mx, __shfl_xor(mx, 32, 64));
      if (!__all(mx <= m + 8.f)) {         // defer-max (T13)
        float mnew = fmaxf(m, mx);
        float sf = __expf(m - mnew);
        lsum *= sf;
#pragma unroll
        for (int d0 = 0; d0 < 4; d0++)
#pragma unroll
          for (int r = 0; r < 16; r++) o[d0][r] *= sf;
        m = mnew;
      }
      float ps = 0.f;
#pragma unroll
      for (int r = 0; r < 16; r++) { s[r] = __expf(s[r] - m); ps += s[r]; }
      lsum += ps + __shfl_xor(ps, 32, 64);
      // ---- P -> bf16 fragments, PV from LDS V^T ----
#pragma unroll
      for (int w2 = 0; w2 < 2; w2++) {
        unsigned c01 = cvtpk_bf16(s[w2*8+0], s[w2*8+1]);
        unsigned c23 = cvtpk_bf16(s[w2*8+2], s[w2*8+3]);
        unsigned c45 = cvtpk_bf16(s[w2*8+4], s[w2*8+5]);
        unsigned c67 = cvtpk_bf16(s[w2*8+6], s[w2*8+7]);
        unsigned x01 = (unsigned)__shfl_xor((int)c01, 32, 64);
        unsigned x23 = (unsigned)__shfl_xor((int)c23, 32, 64);
        unsigned x45 = (unsigned)__shfl_xor((int)c45, 32, 64);
        unsigned x67 = (unsigned)__shfl_xor((int)c67, 32, 64);
        union { unsigned u[4]; bf16x8 v; } pb;
        pb.u[0] = hi ? x45 : c01;
        pb.u[1] = hi ? x67 : c23;
        pb.u[2] = hi ? c45 : x01;
        pb.u[3] = hi ? c67 : x23;
#pragma unroll
        for (int d0 = 0; d0 < 4; d0++) {
          bf16x8 vf = *(const bf16x8*)(VB + (d0 * 32 + col) * VSTRIDE + ((32 * w2 + 16 * hi) ^ ((col & 3) << 4)));
          o[d0] = __builtin_amdgcn_mfma_f32_32x32x16_bf16(vf, pb.v, o[d0], 0, 0, 0);
        }
      }
    }
    __syncthreads();                       // drains stage(t+1) + read-done on cur
    cur ^= 1;
  }

  // ---- epilogue: per-wave O^T -> O transpose in reused LDS ----
  float* tr = (float*)(lds + wave * 4352); // 32*33*4 = 4224B per wave
  float inv = 1.f / lsum;
  unsigned short* orow = AttO + (size_t)(b * L_SEQ + q0 + col) * D_MODEL + h * HD;
#pragma unroll
  for (int d0 = 0; d0 < 4; d0++) {
#pragma unroll
    for (int r = 0; r < 16; r++)
      tr[((r & 3) + 8 * (r >> 2) + 4 * hi) * 33 + col] = o[d0][r] * inv;
    __syncthreads();
    union { unsigned u[8]; } pk;
#pragma unroll
    for (int t = 0; t < 8; t++) {
      float a  = tr[(hi * 16 + 2 * t) * 33 + col];
      float bb = tr[(hi * 16 + 2 * t + 1) * 33 + col];
      pk.u[t] = ((unsigned)f2b(a)) | (((unsigned)f2b(bb)) << 16);
    }
    *(uint4*)(orow + d0 * 32 + hi * 16)     = *(uint4*)&pk.u[0];
    *(uint4*)(orow + d0 * 32 + hi * 16 + 8) = *(uint4*)&pk.u[4];
    __syncthreads();
  }
}

extern "C" void kernel_launch(void* const* d_in, const int* in_sizes, int n_in,
                              void* d_out, int out_size, void* d_ws, size_t ws_size,
                              hipStream_t stream) {
  const float* x    = (const float*)d_in[0];
  const float* cosp = (const float*)d_in[1];
  const float* sinp = (const float*)d_in[2];
  const float* Wq   = (const float*)d_in[3];
  const float* Wk   = (const float*)d_in[4];
  const float* Wv   = (const float*)d_in[5];
  const float* Wo   = (const float*)d_in[6];
  float* out = (float*)d_out;

  char* ws = (char*)d_ws;
  unsigned short* Xb   = (unsigned short*)ws; ws += (size_t)M_ROWS * D_MODEL * 2;
  unsigned short* Wt   = (unsigned short*)ws; ws += (size_t)N_QKV * D_MODEL * 2;
  unsigned short* Wot  = (unsigned short*)ws; ws += (size_t)D_MODEL * D_MODEL * 2;
  float*          QKV  = (float*)ws;          ws += (size_t)M_ROWS * N_QKV * 4;
  unsigned short* Qb   = (unsigned short*)ws; ws += (size_t)BATCH * NH * L_SEQ * HD * 2;
  unsigned short* Kb   = (unsigned short*)ws; ws += (size_t)BATCH * NKV * L_SEQ * HD * 2;
  unsigned short* Vt   = (unsigned short*)ws; ws += (size_t)BATCH * NKV * HD * L_SEQ * 2;
  unsigned short* AttO = (unsigned short*)ws; ws += (size_t)M_ROWS * D_MODEL * 2;

  cvt_bf16_kernel<<<(M_ROWS * D_MODEL / 4 + 255) / 256, 256, 0, stream>>>(x, Xb, M_ROWS * D_MODEL / 4);
  build_wqkv_t<<<dim3(64, 96), dim3(32, 8), 0, stream>>>(Wq, Wk, Wv, Wt);
  build_wo_t<<<dim3(64, 64), dim3(32, 8), 0, stream>>>(Wo, Wot);
  gemm_bt<<<dim3(N_QKV / BN, M_ROWS / BM), 256, 0, stream>>>(Xb, Wt, QKV, M_ROWS, N_QKV, D_MODEL);
  rope_rms_kernel<<<M_ROWS, 256, 0, stream>>>(QKV, cosp, sinp, Qb, Kb);
  vt_build<<<dim3(64, 4, 8), dim3(32, 8), 0, stream>>>(QKV, Vt);
  attn128_kernel<<<dim3(512), 256, 0, stream>>>(Qb, Kb, Vt, AttO);
  gemm_bt<<<dim3(D_MODEL / BN, M_ROWS / BM), 256, 0, stream>>>(AttO, Wot, out, M_ROWS, D_MODEL, D_MODEL);
}

// Round 7
// 336.995 us; speedup vs baseline: 1.8351x; 1.0044x over previous
//
#include <hip/hip_runtime.h>
#include <stdint.h>

#define D_MODEL 2048
#define L_SEQ   2048
#define BATCH   2
#define NH      16
#define NKV     4
#define HD      128
#define ROT     64
#define M_ROWS  (BATCH * L_SEQ)            // 4096
#define N_QKV   (D_MODEL + 2 * NKV * HD)   // 3072

typedef short bf16x8 __attribute__((ext_vector_type(8)));
typedef float f32x4  __attribute__((ext_vector_type(4)));
typedef float f32x16 __attribute__((ext_vector_type(16)));

__device__ __forceinline__ unsigned short f2b(float f) {
  union { float f; unsigned u; } v; v.f = f;
  unsigned r = v.u + 0x7FFFu + ((v.u >> 16) & 1u);
  return (unsigned short)(r >> 16);
}

__device__ __forceinline__ float b2f(unsigned short u) {
  union { unsigned u; float f; } v; v.u = ((unsigned)u) << 16; return v.f;
}

__device__ __forceinline__ unsigned cvtpk_bf16(float a, float b) {
  unsigned r;
  asm("v_cvt_pk_bf16_f32 %0, %1, %2" : "=v"(r) : "v"(a), "v"(b));
  return r;
}

// ---------------- elementwise fp32 -> bf16 ----------------
__global__ void cvt_bf16_kernel(const float* __restrict__ in,
                                unsigned short* __restrict__ out, int n4) {
  int i = blockIdx.x * blockDim.x + threadIdx.x;
  if (i < n4) {
    float4 v = ((const float4*)in)[i];
    ushort4 o;
    o.x = f2b(v.x); o.y = f2b(v.y); o.z = f2b(v.z); o.w = f2b(v.w);
    ((ushort4*)out)[i] = o;
  }
}

// ---------------- build Wqkv^T (3072 x 2048) bf16 ----------------
__global__ void build_wqkv_t(const float* __restrict__ Wq, const float* __restrict__ Wk,
                             const float* __restrict__ Wv, unsigned short* __restrict__ Wt) {
  __shared__ float tile[32][33];
  int k0 = blockIdx.x * 32;
  int n0 = blockIdx.y * 32;
  const float* W; int c0, ldw;
  if (n0 < D_MODEL)            { W = Wq; c0 = n0;                 ldw = D_MODEL; }
  else if (n0 < D_MODEL + 512) { W = Wk; c0 = n0 - D_MODEL;       ldw = 512; }
  else                         { W = Wv; c0 = n0 - D_MODEL - 512; ldw = 512; }
  int tx = threadIdx.x, ty = threadIdx.y;
#pragma unroll
  for (int i = 0; i < 32; i += 8)
    tile[ty + i][tx] = W[(size_t)(k0 + ty + i) * ldw + c0 + tx];
  __syncthreads();
#pragma unroll
  for (int i = 0; i < 32; i += 8)
    Wt[(size_t)(n0 + ty + i) * D_MODEL + k0 + tx] = f2b(tile[tx][ty + i]);
}

// ---------------- build Wo^T (2048 x 2048) bf16 ----------------
__global__ void build_wo_t(const float* __restrict__ Wo, unsigned short* __restrict__ Wt) {
  __shared__ float tile[32][33];
  int k0 = blockIdx.x * 32;
  int n0 = blockIdx.y * 32;
  int tx = threadIdx.x, ty = threadIdx.y;
#pragma unroll
  for (int i = 0; i < 32; i += 8)
    tile[ty + i][tx] = Wo[(size_t)(k0 + ty + i) * D_MODEL + n0 + tx];
  __syncthreads();
#pragma unroll
  for (int i = 0; i < 32; i += 8)
    Wt[(size_t)(n0 + ty + i) * D_MODEL + k0 + tx] = f2b(tile[tx][ty + i]);
}

// ---------------- m97-style bf16 GEMM, B^T input, fp32 or bf16 out ----------------
#define BM 128
#define BN 128
#define BKg 64

__device__ __forceinline__ void async16(void* lds, const void* g) {
  __builtin_amdgcn_global_load_lds((const __attribute__((address_space(1))) void*)g,
                                   (__attribute__((address_space(3))) void*)lds, 16, 0, 0);
}

template<bool BF16OUT>
__global__ __launch_bounds__(256, 2)
void gemm_bt(const unsigned short* __restrict__ A, const unsigned short* __restrict__ Bt,
             void* __restrict__ Cv, int M, int N, int K) {
  __shared__ unsigned short As[BM * BKg];
  __shared__ unsigned short Bs[BN * BKg];
  int m0 = blockIdx.y * BM;
  int n0 = blockIdx.x * BN;
  int tid = threadIdx.x;
  int lane = tid & 63;
  int wave = __builtin_amdgcn_readfirstlane(tid >> 6);
  int wr = wave >> 1, wc = wave & 1;
  int lgrp = lane >> 4, lidx = lane & 15;

  f32x4 acc[4][4];
#pragma unroll
  for (int i = 0; i < 4; i++)
#pragma unroll
    for (int j = 0; j < 4; j++) { acc[i][j][0]=0.f; acc[i][j][1]=0.f; acc[i][j][2]=0.f; acc[i][j][3]=0.f; }

  for (int k0 = 0; k0 < K; k0 += BKg) {
#pragma unroll
    for (int iss = 0; iss < 4; iss++) {
      int idx = iss * 256 + tid;
      int row = idx >> 3, cch = idx & 7;
      int lbase = (iss * 256 + wave * 64) * 8;   // elements
      async16((void*)(As + lbase), A  + (size_t)(m0 + row) * K + k0 + cch * 8);
      async16((void*)(Bs + lbase), Bt + (size_t)(n0 + row) * K + k0 + cch * 8);
    }
    __syncthreads();
#pragma unroll
    for (int kk = 0; kk < BKg; kk += 32) {
      bf16x8 af[4], bfr[4];
#pragma unroll
      for (int i = 0; i < 4; i++) {
        af[i]  = *(const bf16x8*)(As + (wr * 64 + i * 16 + lidx) * BKg + kk + lgrp * 8);
        bfr[i] = *(const bf16x8*)(Bs + (wc * 64 + i * 16 + lidx) * BKg + kk + lgrp * 8);
      }
#pragma unroll
      for (int i = 0; i < 4; i++)
#pragma unroll
        for (int j = 0; j < 4; j++)
          acc[i][j] = __builtin_amdgcn_mfma_f32_16x16x32_bf16(af[i], bfr[j], acc[i][j], 0, 0, 0);
    }
    __syncthreads();
  }
#pragma unroll
  for (int i = 0; i < 4; i++) {
    int rowb = m0 + wr * 64 + i * 16 + lgrp * 4;
#pragma unroll
    for (int j = 0; j < 4; j++) {
      int col = n0 + wc * 64 + j * 16 + lidx;
#pragma unroll
      for (int r = 0; r < 4; r++) {
        if constexpr (BF16OUT)
          ((unsigned short*)Cv)[(size_t)(rowb + r) * N + col] = f2b(acc[i][j][r]);
        else
          ((float*)Cv)[(size_t)(rowb + r) * N + col] = acc[i][j][r];
      }
    }
  }
}

// ---------------- rope + qk-rmsnorm from bf16 QKV, writes Q/K bf16 per-(b,h) L x 128 ----------------
__global__ __launch_bounds__(256)
void rope_rms_kernel(const unsigned short* __restrict__ QKV, const float* __restrict__ cosp,
                     const float* __restrict__ sinp, unsigned short* __restrict__ Qb,
                     unsigned short* __restrict__ Kb) {
  int row = blockIdx.x;                    // b*L + l
  int b = row >> 11, l = row & 2047;
  int lane = threadIdx.x & 63;
  int wave = threadIdx.x >> 6;
  const unsigned short* src = QKV + (size_t)row * N_QKV;
  float c = cosp[l * ROT + lane];
  float s = sinp[l * ROT + lane];
  for (int hh = wave; hh < NH + NKV; hh += 4) {
    bool isq = hh < NH;
    int col0 = isq ? hh * HD : D_MODEL + (hh - NH) * HD;
    float x1 = b2f(src[col0 + lane]);
    float x2 = b2f(src[col0 + 64 + lane]);
    float o1 = x1 * c - x2 * s;
    float o2 = x2 * c + x1 * s;
    float ss = o1 * o1 + o2 * o2;
#pragma unroll
    for (int mk = 1; mk < 64; mk <<= 1) ss += __shfl_xor(ss, mk, 64);
    float rn = rsqrtf(ss * (1.f / 128.f) + 1e-6f);
    if (isq) rn *= 0.08838834764831845f;   // fold 1/sqrt(HD) into Q
    o1 *= rn; o2 *= rn;
    unsigned short* dst = isq ? (Qb + ((size_t)(b * NH + hh) * L_SEQ + l) * HD)
                              : (Kb + ((size_t)(b * NKV + (hh - NH)) * L_SEQ + l) * HD);
    dst[lane]      = f2b(o1);
    dst[lane + 64] = f2b(o2);
  }
}

// ---------------- V^T build from bf16 QKV: (b,kvh) 128 x L bf16 ----------------
__global__ void vt_build(const unsigned short* __restrict__ QKV, unsigned short* __restrict__ Vt) {
  __shared__ unsigned short tile[32][33];
  int z = blockIdx.z;                      // b*NKV + kh
  int l0 = blockIdx.x * 32;
  int d0 = blockIdx.y * 32;
  int b = z >> 2, kh = z & 3;
  int tx = threadIdx.x, ty = threadIdx.y;
  int colbase = D_MODEL + NKV * HD + kh * HD + d0;
#pragma unroll
  for (int i = 0; i < 32; i += 8)
    tile[ty + i][tx] = QKV[(size_t)(b * L_SEQ + l0 + ty + i) * N_QKV + colbase + tx];
  __syncthreads();
#pragma unroll
  for (int i = 0; i < 32; i += 8)
    Vt[((size_t)z * HD + d0 + ty + i) * L_SEQ + l0 + tx] = tile[tx][ty + i];
}

// ---------------- flash attention: 2 waves/block share K,V via LDS, 4 blocks/CU ----------------
// Block = 64 q-rows of one (b,h); wave w owns rows [q0+32w, q0+32w+32).
// qt' = (blk&31) ^ (blk>>5): spatial length-mixing so any dispatch order gives each
// CU a balanced mix of long/short blocks (1024 blocks = exactly 4/CU, no backfill).
// K tile [32][128] bf16 (8KB) + V^T tile [128][32] bf16 (8KB), double-buffered (32KB).
// T2 swizzle per rule #21: linear LDS dest (global_load_lds) + inverse-swizzled
// global SOURCE + swizzled ds_read. K: byte^=(row&7)<<4; V^T: byte^=(row&3)<<4.
// S^T = mfma_32x32x16(A=K, B=Q); 32x32 C/D: row=(reg&3)+8*(reg>>2)+4*hi, col=lane&31.
#define KSTRIDE 256   // bytes per K row (128 bf16)
#define VSTRIDE 64    // bytes per V^T row (32 bf16)
#define TILEB   16384 // K(8KB)+V(8KB) per buffer

__global__ __launch_bounds__(128, 2)
void attn64_kernel(const unsigned short* __restrict__ Qb, const unsigned short* __restrict__ Kb,
                   const unsigned short* __restrict__ Vt, unsigned short* __restrict__ AttO) {
  __shared__ char lds[2 * TILEB];
  int blk = blockIdx.x;
  int bh = blk >> 5;
  int qt = (blk & 31) ^ bh;                // length-mixed q-tile of 64 rows
  int b = bh >> 4, h = bh & 15, kh = h >> 2;
  int tid = threadIdx.x;
  int lane = tid & 63;
  int wave = __builtin_amdgcn_readfirstlane(tid >> 6);   // 0..1
  int col = lane & 31;
  int hi  = lane >> 5;
  int q0 = qt * 64 + wave * 32;

  const unsigned short* Q   = Qb + ((size_t)(b * NH + h) * L_SEQ + q0) * HD;
  const unsigned short* Kg  = Kb + (size_t)(b * NKV + kh) * L_SEQ * HD;
  const unsigned short* Vtg = Vt + (size_t)(b * NKV + kh) * HD * L_SEQ;  // [128][L]

  bf16x8 qf[8];
#pragma unroll
  for (int c = 0; c < 8; c++)
    qf[c] = *(const bf16x8*)(Q + (size_t)col * HD + c * 16 + hi * 8);

  f32x16 o[4];
#pragma unroll
  for (int d0 = 0; d0 < 4; d0++)
#pragma unroll
    for (int r = 0; r < 16; r++) o[d0][r] = 0.f;
  float m = -1e30f, lsum = 0.f;

  int NT = 2 * (qt + 1);                   // kv tiles this block walks
  int tmax = 2 * qt + wave;                // last tile this wave computes (diagonal)

  // ---- stage tile t into buffer base (global_load_lds, pre-swizzled source) ----
  auto STAGE = [&](char* base, int t) {
    int kv0 = t * 32;
    char* ldsK = base;
    char* ldsV = base + 8192;
    int wb = wave * 64;                    // wave-uniform slot base within round
#pragma unroll
    for (int r = 0; r < 4; r++) {
      int slot = r * 128 + tid;            // 0..511
      int row = slot >> 4, s16 = slot & 15;
      const char* src = (const char*)Kg + (size_t)(kv0 + row) * KSTRIDE + ((s16 ^ (row & 7)) << 4);
      async16(ldsK + (size_t)(r * 128 + wb) * 16, src);
    }
#pragma unroll
    for (int r = 0; r < 4; r++) {
      int slot = r * 128 + tid;
      int row = slot >> 2, s4 = slot & 3;
      const char* src = (const char*)Vtg + (size_t)row * (L_SEQ * 2) + (size_t)kv0 * 2 + ((s4 ^ (row & 3)) << 4);
      async16(ldsV + (size_t)(r * 128 + wb) * 16, src);
    }
  };

  STAGE(lds, 0);
  __syncthreads();                         // drains vmcnt -> tile 0 ready

  int cur = 0;
  for (int t = 0; t < NT; t++) {
    if (t + 1 < NT) STAGE(lds + (cur ^ 1) * TILEB, t + 1);

    if (t <= tmax) {
      const char* KB = lds + cur * TILEB;
      const char* VB = KB + 8192;
      // ---- S^T: 8 mfma, two chains ----
      f32x16 sA, sB;
#pragma unroll
      for (int r = 0; r < 16; r++) { sA[r] = 0.f; sB[r] = 0.f; }
#pragma unroll
      for (int c = 0; c < 4; c++) {
        bf16x8 kf = *(const bf16x8*)(KB + col * KSTRIDE + ((32 * c + 16 * hi) ^ ((col & 7) << 4)));
        sA = __builtin_amdgcn_mfma_f32_32x32x16_bf16(kf, qf[c], sA, 0, 0, 0);
      }
#pragma unroll
      for (int c = 4; c < 8; c++) {
        bf16x8 kf = *(const bf16x8*)(KB + col * KSTRIDE + ((32 * c + 16 * hi) ^ ((col & 7) << 4)));
        sB = __builtin_amdgcn_mfma_f32_32x32x16_bf16(kf, qf[c], sB, 0, 0, 0);
      }
      f32x16 s = sA + sB;
      // ---- causal mask (diagonal tile only) ----
      if (t == tmax) {
#pragma unroll
        for (int r = 0; r < 16; r++) {
          int kvl = (r & 3) + 8 * (r >> 2) + 4 * hi;
          if (kvl > col) s[r] = -1e30f;
        }
      }
      // ---- online softmax, in-register ----
      float mx = s[0];
#pragma unroll
      for (int r = 1; r < 16; r++) mx = fmaxf(mx, s[r]);
      mx = fmaxf(mx, __shfl_xor(mx, 32, 64));
      if (!__all(mx <= m + 8.f)) {         // defer-max (T13)
        float mnew = fmaxf(m, mx);
        float sf = __expf(m - mnew);
        lsum *= sf;
#pragma unroll
        for (int d0 = 0; d0 < 4; d0++)
#pragma unroll
          for (int r = 0; r < 16; r++) o[d0][r] *= sf;
        m = mnew;
      }
      float ps = 0.f;
#pragma unroll
      for (int r = 0; r < 16; r++) { s[r] = __expf(s[r] - m); ps += s[r]; }
      lsum += ps + __shfl_xor(ps, 32, 64);
      // ---- P -> bf16 fragments, PV from LDS V^T ----
#pragma unroll
      for (int w2 = 0; w2 < 2; w2++) {
        unsigned c01 = cvtpk_bf16(s[w2*8+0], s[w2*8+1]);
        unsigned c23 = cvtpk_bf16(s[w2*8+2], s[w2*8+3]);
        unsigned c45 = cvtpk_bf16(s[w2*8+4], s[w2*8+5]);
        unsigned c67 = cvtpk_bf16(s[w2*8+6], s[w2*8+7]);
        unsigned x01 = (unsigned)__shfl_xor((int)c01, 32, 64);
        unsigned x23 = (unsigned)__shfl_xor((int)c23, 32, 64);
        unsigned x45 = (unsigned)__shfl_xor((int)c45, 32, 64);
        unsigned x67 = (unsigned)__shfl_xor((int)c67, 32, 64);
        union { unsigned u[4]; bf16x8 v; } pb;
        pb.u[0] = hi ? x45 : c01;
        pb.u[1] = hi ? x67 : c23;
        pb.u[2] = hi ? c45 : x01;
        pb.u[3] = hi ? c67 : x23;
#pragma unroll
        for (int d0 = 0; d0 < 4; d0++) {
          bf16x8 vf = *(const bf16x8*)(VB + (d0 * 32 + col) * VSTRIDE + ((32 * w2 + 16 * hi) ^ ((col & 3) << 4)));
          o[d0] = __builtin_amdgcn_mfma_f32_32x32x16_bf16(vf, pb.v, o[d0], 0, 0, 0);
        }
      }
    }
    __syncthreads();                       // drains stage(t+1) + read-done on cur
    cur ^= 1;
  }

  // ---- epilogue: per-wave O^T -> O transpose in reused LDS ----
  float* tr = (float*)(lds + wave * 4352); // 32*33*4 = 4224B per wave
  float inv = 1.f / lsum;
  unsigned short* orow = AttO + (size_t)(b * L_SEQ + q0 + col) * D_MODEL + h * HD;
#pragma unroll
  for (int d0 = 0; d0 < 4; d0++) {
#pragma unroll
    for (int r = 0; r < 16; r++)
      tr[((r & 3) + 8 * (r >> 2) + 4 * hi) * 33 + col] = o[d0][r] * inv;
    __syncthreads();
    union { unsigned u[8]; } pk;
#pragma unroll
    for (int t = 0; t < 8; t++) {
      float a  = tr[(hi * 16 + 2 * t) * 33 + col];
      float bb = tr[(hi * 16 + 2 * t + 1) * 33 + col];
      pk.u[t] = ((unsigned)f2b(a)) | (((unsigned)f2b(bb)) << 16);
    }
    *(uint4*)(orow + d0 * 32 + hi * 16)     = *(uint4*)&pk.u[0];
    *(uint4*)(orow + d0 * 32 + hi * 16 + 8) = *(uint4*)&pk.u[4];
    __syncthreads();
  }
}

extern "C" void kernel_launch(void* const* d_in, const int* in_sizes, int n_in,
                              void* d_out, int out_size, void* d_ws, size_t ws_size,
                              hipStream_t stream) {
  const float* x    = (const float*)d_in[0];
  const float* cosp = (const float*)d_in[1];
  const float* sinp = (const float*)d_in[2];
  const float* Wq   = (const float*)d_in[3];
  const float* Wk   = (const float*)d_in[4];
  const float* Wv   = (const float*)d_in[5];
  const float* Wo   = (const float*)d_in[6];
  float* out = (float*)d_out;

  char* ws = (char*)d_ws;
  unsigned short* Xb   = (unsigned short*)ws; ws += (size_t)M_ROWS * D_MODEL * 2;
  unsigned short* Wt   = (unsigned short*)ws; ws += (size_t)N_QKV * D_MODEL * 2;
  unsigned short* Wot  = (unsigned short*)ws; ws += (size_t)D_MODEL * D_MODEL * 2;
  unsigned short* QKVb = (unsigned short*)ws; ws += (size_t)M_ROWS * N_QKV * 4;  // slot kept fp32-sized
  unsigned short* Qb   = (unsigned short*)ws; ws += (size_t)BATCH * NH * L_SEQ * HD * 2;
  unsigned short* Kb   = (unsigned short*)ws; ws += (size_t)BATCH * NKV * L_SEQ * HD * 2;
  unsigned short* Vt   = (unsigned short*)ws; ws += (size_t)BATCH * NKV * HD * L_SEQ * 2;
  unsigned short* AttO = (unsigned short*)ws; ws += (size_t)M_ROWS * D_MODEL * 2;

  cvt_bf16_kernel<<<(M_ROWS * D_MODEL / 4 + 255) / 256, 256, 0, stream>>>(x, Xb, M_ROWS * D_MODEL / 4);
  build_wqkv_t<<<dim3(64, 96), dim3(32, 8), 0, stream>>>(Wq, Wk, Wv, Wt);
  build_wo_t<<<dim3(64, 64), dim3(32, 8), 0, stream>>>(Wo, Wot);
  gemm_bt<true><<<dim3(N_QKV / BN, M_ROWS / BM), 256, 0, stream>>>(Xb, Wt, QKVb, M_ROWS, N_QKV, D_MODEL);
  rope_rms_kernel<<<M_ROWS, 256, 0, stream>>>(QKVb, cosp, sinp, Qb, Kb);
  vt_build<<<dim3(64, 4, 8), dim3(32, 8), 0, stream>>>(QKVb, Vt);
  attn64_kernel<<<dim3(1024), 128, 0, stream>>>(Qb, Kb, Vt, AttO);
  gemm_bt<false><<<dim3(D_MODEL / BN, M_ROWS / BM), 256, 0, stream>>>(AttO, Wot, out, M_ROWS, D_MODEL, D_MODEL);
}